// Round 4
// baseline (386.780 us; speedup 1.0000x reference)
//
#include <hip/hip_runtime.h>
#include <hip/hip_bf16.h>
#include <math.h>

#define BATCH 64
#define CH    768
#define NP    1024
#define NI    96
#define NT    8
#define EPSF  1e-5f

typedef __attribute__((ext_vector_type(8))) short  short8;
typedef __attribute__((ext_vector_type(4))) float  f32x4;

__device__ __forceinline__ short bfs(float f) {
    __hip_bfloat16 h = __float2bfloat16(f);   // RTNE; pairs fuse to v_cvt_pk_bf16_f32
    return *reinterpret_cast<short*>(&h);
}

// ---------------- Kernel 0: prep ----------------
// blocks 0..71: pack w1g = gamma (.) w1 (fp32 [768][96]) -> bf16 B-fragment layout:
//   w1f[((ks*6+nt)*64 + l)*8 + j] = bf16(gamma[c]*w1[c, nt*16+(l&15)]), c = ks*32+(l>>4)*8+j
// block 72: c1[n] = b1[n] + sum_c beta_c*w1[c,n];  gw1[n] = sum_c gamma_c*w1[c,n]
__global__ __launch_bounds__(128) void k_prep(const float* __restrict__ w1,
        const float* __restrict__ gamma, const float* __restrict__ beta,
        const float* __restrict__ b1,
        unsigned short* __restrict__ w1f, float* __restrict__ c1, float* __restrict__ gw1)
{
    int bid = blockIdx.x;
    if (bid < 72) {
        int slot = bid * 128 + threadIdx.x;   // 0..9215  (144 frag-blocks x 64 lanes)
        int l    = slot & 63;
        int blk  = slot >> 6;
        int ks   = blk / 6, nt = blk % 6;
        int n    = nt * 16 + (l & 15);
        int k0   = ks * 32 + (l >> 4) * 8;
        short8 o;
#pragma unroll
        for (int j = 0; j < 8; ++j)
            o[j] = bfs(gamma[k0 + j] * w1[(size_t)(k0 + j) * NI + n]);
        *(short8*)(w1f + (size_t)slot * 8) = o;
    } else {
        int n = threadIdx.x;
        if (n < NI) {
            float bw = 0.f, gw = 0.f;
#pragma unroll 4
            for (int c = 0; c < CH; ++c) {
                float w = w1[(size_t)c * NI + n];
                bw = fmaf(beta[c],  w, bw);
                gw = fmaf(gamma[c], w, gw);
            }
            c1[n]  = bw + b1[n];
            gw1[n] = gw;
        }
    }
}

// ---------------- Kernel 1: single-pass stats + GEMM(x@w1g) + gelu + w2 -> logits, stats ----------------
// grid BATCH*8, block 256 (4 waves x 32-token tiles). A-frag = bf16(raw x); LN folded:
// h_pre[p,n] = rstd_p*G[p,n] + c1[n] - (mu_p*rstd_p)*gw1[n],  G = x @ (gamma.*w1)
__global__ __launch_bounds__(256) void k_mlpf(const float* __restrict__ x,
        const unsigned short* __restrict__ w1f,
        const float* __restrict__ c1, const float* __restrict__ gw1,
        const float* __restrict__ w2, const float* __restrict__ b2,
        float2* __restrict__ stats, float* __restrict__ logits)
{
    int bid  = blockIdx.x;
    int b    = bid >> 3;
    int p0   = (bid & 7) << 7;       // 128 tokens per block
    int wv   = threadIdx.x >> 6;
    int lane = threadIdx.x & 63;
    int m    = lane & 15;
    int kg   = lane >> 4;
    int mt   = p0 + wv * 32;         // wave's 32-token tile

    const float* xb = x + (size_t)b * CH * NP + mt + m;

    f32x4 accA[6], accB[6];
#pragma unroll
    for (int nt = 0; nt < 6; ++nt) {
        accA[nt] = (f32x4){0.f,0.f,0.f,0.f};
        accB[nt] = (f32x4){0.f,0.f,0.f,0.f};
    }
    float s0 = 0.f, q0 = 0.f, s1 = 0.f, q1 = 0.f;
    const short8* wfp = (const short8*)w1f;

    for (int ks = 0; ks < 24; ++ks) {
        int cb = ks * 32 + kg * 8;
        const float* xc = xb + (size_t)cb * NP;
        float xv0[8], xv1[8];
#pragma unroll
        for (int j = 0; j < 8; ++j) {
            xv0[j] = xc[(size_t)j * NP];
            xv1[j] = xc[(size_t)j * NP + 16];
        }
        short8 a0, a1;
#pragma unroll
        for (int j = 0; j < 8; ++j) {
            s0 += xv0[j]; q0 = fmaf(xv0[j], xv0[j], q0);
            s1 += xv1[j]; q1 = fmaf(xv1[j], xv1[j], q1);
            a0[j] = bfs(xv0[j]);
            a1[j] = bfs(xv1[j]);
        }
        const short8* wk = wfp + (size_t)ks * 6 * 64 + lane;
#pragma unroll
        for (int nt = 0; nt < 6; ++nt) {
            short8 bf = wk[nt * 64];
            accA[nt] = __builtin_amdgcn_mfma_f32_16x16x32_bf16(a0, bf, accA[nt], 0, 0, 0);
            accB[nt] = __builtin_amdgcn_mfma_f32_16x16x32_bf16(a1, bf, accB[nt], 0, 0, 0);
        }
    }

    // cross-kg reduce of per-token stats (lanes with same m): xor 16, 32
    s0 += __shfl_xor(s0, 16, 64); s0 += __shfl_xor(s0, 32, 64);
    q0 += __shfl_xor(q0, 16, 64); q0 += __shfl_xor(q0, 32, 64);
    s1 += __shfl_xor(s1, 16, 64); s1 += __shfl_xor(s1, 32, 64);
    q1 += __shfl_xor(q1, 16, 64); q1 += __shfl_xor(q1, 32, 64);
    const float invC = 1.0f / (float)CH;
    float mu0 = s0 * invC, var0 = fmaf(-mu0, mu0, q0 * invC);
    float mu1 = s1 * invC, var1 = fmaf(-mu1, mu1, q1 * invC);
    float rstd0 = rsqrtf(var0 + EPSF), rstd1 = rsqrtf(var1 + EPSF);
    float mr0 = mu0 * rstd0, mr1 = mu1 * rstd1;

    if (kg == 0) {   // one writer per token
        float2* st = stats + (size_t)b * NP + mt + m;
        st[0]  = make_float2(mr0, rstd0);
        st[16] = make_float2(mr1, rstd1);
    }

    // redistribute stats to D-fragment rows: token t = kg*4 + r (per half)
    float mrs0[4], rss0[4], mrs1[4], rss1[4];
#pragma unroll
    for (int r = 0; r < 4; ++r) {
        int src = 4 * kg + r;
        mrs0[r] = __shfl(mr0,   src, 64);
        rss0[r] = __shfl(rstd0, src, 64);
        mrs1[r] = __shfl(mr1,   src, 64);
        rss1[r] = __shfl(rstd1, src, 64);
    }

    // epilogue: h = gelu(rstd*G + c1 - mr*gw1); logits = h @ w2 + b2
    int nlo = lane & 15;
    float4 b2a = *(const float4*)b2;
    float4 b2b = *(const float4*)(b2 + 4);
#pragma unroll
    for (int half = 0; half < 2; ++half) {
        float lg[4][8];
#pragma unroll
        for (int r = 0; r < 4; ++r)
#pragma unroll
            for (int t = 0; t < 8; ++t) lg[r][t] = 0.f;
#pragma unroll
        for (int nt = 0; nt < 6; ++nt) {
            int n = nt * 16 + nlo;
            float c1v  = c1[n];
            float gw1v = gw1[n];
            float4 w2a = *(const float4*)(w2 + n * 8);
            float4 w2b = *(const float4*)(w2 + n * 8 + 4);
            f32x4 ac = half ? accB[nt] : accA[nt];
#pragma unroll
            for (int r = 0; r < 4; ++r) {
                float rs = half ? rss1[r] : rss0[r];
                float mr = half ? mrs1[r] : mrs0[r];
                float h = fmaf(rs, ac[r], fmaf(-mr, gw1v, c1v));
                h = 0.5f * h * (1.0f + erff(h * 0.70710678118654752f));
                lg[r][0] += h * w2a.x; lg[r][1] += h * w2a.y;
                lg[r][2] += h * w2a.z; lg[r][3] += h * w2a.w;
                lg[r][4] += h * w2b.x; lg[r][5] += h * w2b.y;
                lg[r][6] += h * w2b.z; lg[r][7] += h * w2b.w;
            }
        }
#pragma unroll
        for (int mask = 1; mask <= 8; mask <<= 1)
#pragma unroll
            for (int r = 0; r < 4; ++r)
#pragma unroll
                for (int t = 0; t < 8; ++t)
                    lg[r][t] += __shfl_xor(lg[r][t], mask, 64);
        if (nlo == 0) {
#pragma unroll
            for (int r = 0; r < 4; ++r) {
                int pp = mt + half * 16 + kg * 4 + r;
                float* op = logits + ((size_t)b * NP + pp) * NT;
                *(float4*)op       = make_float4(lg[r][0] + b2a.x, lg[r][1] + b2a.y,
                                                 lg[r][2] + b2a.z, lg[r][3] + b2a.w);
                *(float4*)(op + 4) = make_float4(lg[r][4] + b2b.x, lg[r][5] + b2b.y,
                                                 lg[r][6] + b2b.z, lg[r][7] + b2b.w);
            }
        }
    }
}

// ---------------- Kernel 2: fused softmax + out-GEMM ----------------
// grid BATCH*12 (64 channels each), block 256 (4 waves). Each block redoes the cheap
// softmax over its batch's 1024 tokens from logits (LLC-warm), packs g = rstd*attn
// into bf16 B-frags in LDS, then out[c,n] = (gamma_c*(x[c,:]·g[:,n] - S2[n]) + beta_c)/1024.
__global__ __launch_bounds__(256) void k_outg(const float* __restrict__ x,
        const float* __restrict__ logits, const float2* __restrict__ stats,
        const float* __restrict__ gamma, const float* __restrict__ beta,
        float* __restrict__ out)
{
    int b   = blockIdx.x / 12;
    int c0  = (blockIdx.x % 12) * 64;
    int tid = threadIdx.x;
    int lane = tid & 63, wv = tid >> 6;

    __shared__ unsigned short gfrag[2048 * 8];  // 32 KB: B-frags, 32 ks-tiles x 64 lanes x 8
    __shared__ float red[4][16];
    __shared__ float s2s[NT];

    // ---- phase A: softmax over 1024 tokens ----
    const float* lgp = logits + (size_t)b * NP * NT;
    const float2* stb = stats + (size_t)b * NP;   // (mu*rstd, rstd)
    float e[4][NT];
    float2 st4[4];
#pragma unroll
    for (int k = 0; k < 4; ++k) {
        int p = tid + 256 * k;
        float4 a  = *(const float4*)(lgp + (size_t)p * NT);
        float4 bq = *(const float4*)(lgp + (size_t)p * NT + 4);
        e[k][0]=a.x; e[k][1]=a.y; e[k][2]=a.z; e[k][3]=a.w;
        e[k][4]=bq.x; e[k][5]=bq.y; e[k][6]=bq.z; e[k][7]=bq.w;
        st4[k] = stb[p];
    }
    float mx[NT];
#pragma unroll
    for (int t = 0; t < NT; ++t)
        mx[t] = fmaxf(fmaxf(e[0][t], e[1][t]), fmaxf(e[2][t], e[3][t]));
#pragma unroll
    for (int mask = 1; mask <= 32; mask <<= 1)
#pragma unroll
        for (int t = 0; t < NT; ++t)
            mx[t] = fmaxf(mx[t], __shfl_xor(mx[t], mask, 64));
    if (lane == 0) {
#pragma unroll
        for (int t = 0; t < NT; ++t) red[wv][t] = mx[t];
    }
    __syncthreads();
#pragma unroll
    for (int t = 0; t < NT; ++t)
        mx[t] = fmaxf(fmaxf(red[0][t], red[1][t]), fmaxf(red[2][t], red[3][t]));
    __syncthreads();

    float sm[NT], s2p[NT];
#pragma unroll
    for (int t = 0; t < NT; ++t) { sm[t] = 0.f; s2p[t] = 0.f; }
#pragma unroll
    for (int k = 0; k < 4; ++k) {
#pragma unroll
        for (int t = 0; t < NT; ++t) {
            e[k][t] = expf(e[k][t] - mx[t]);
            sm[t]  += e[k][t];
            s2p[t] = fmaf(st4[k].x, e[k][t], s2p[t]);   // (mu*rstd)*e
        }
    }
#pragma unroll
    for (int mask = 1; mask <= 32; mask <<= 1)
#pragma unroll
        for (int t = 0; t < NT; ++t) {
            sm[t]  += __shfl_xor(sm[t],  mask, 64);
            s2p[t] += __shfl_xor(s2p[t], mask, 64);
        }
    if (lane == 0) {
#pragma unroll
        for (int t = 0; t < NT; ++t) { red[wv][t] = sm[t]; }
    }
    __syncthreads();
    float inv[NT];
#pragma unroll
    for (int t = 0; t < NT; ++t)
        inv[t] = 1.0f / (red[0][t] + red[1][t] + red[2][t] + red[3][t]);
    __syncthreads();
    if (lane == 0) {
#pragma unroll
        for (int t = 0; t < NT; ++t) red[wv][t] = s2p[t];
    }
    __syncthreads();
    if (tid < NT)
        s2s[tid] = (red[0][tid] + red[1][tid] + red[2][tid] + red[3][tid]) * inv[tid];

    // zero the n>=8 half of the B-frags (1024 slots x 16 B)
#pragma unroll
    for (int q = 0; q < 4; ++q) {
        int idx  = tid * 4 + q;             // 0..1023
        int slot = (idx >> 3) * 16 + 8 + (idx & 7);
        *(short8*)(gfrag + (size_t)slot * 8) = (short8){0,0,0,0,0,0,0,0};
    }
    // write g = rstd*attn into B-frag layout: token p -> slot (p>>5)*64 + ((p>>3)&3)*16 + n, elem p&7
#pragma unroll
    for (int k = 0; k < 4; ++k) {
        int p = tid + 256 * k;
        int base = ((p >> 5) * 64 + ((p >> 3) & 3) * 16) * 8 + (p & 7);
        float rs = st4[k].y;
#pragma unroll
        for (int t = 0; t < NT; ++t)
            gfrag[base + t * 8] = (unsigned short)bfs(rs * e[k][t] * inv[t]);
    }
    __syncthreads();

    // ---- phase B: MFMA GEMM, M=16 ch/wave, N=16 (8 used), K=1024 ----
    int kg = lane >> 4, m = lane & 15, n = lane & 15;
    int cw = c0 + wv * 16;
    const float*  xr = x + ((size_t)b * CH + cw + m) * NP + kg * 8;
    const short8* gb = (const short8*)gfrag;

    f32x4 acc0 = (f32x4){0.f,0.f,0.f,0.f};
    f32x4 acc1 = (f32x4){0.f,0.f,0.f,0.f};
#pragma unroll 4
    for (int ks = 0; ks < 32; ks += 2) {
        float4 v0 = *(const float4*)(xr + ks * 32);
        float4 v1 = *(const float4*)(xr + ks * 32 + 4);
        float4 v2 = *(const float4*)(xr + ks * 32 + 32);
        float4 v3 = *(const float4*)(xr + ks * 32 + 36);
        short8 a0, a1;
        a0[0]=bfs(v0.x); a0[1]=bfs(v0.y); a0[2]=bfs(v0.z); a0[3]=bfs(v0.w);
        a0[4]=bfs(v1.x); a0[5]=bfs(v1.y); a0[6]=bfs(v1.z); a0[7]=bfs(v1.w);
        a1[0]=bfs(v2.x); a1[1]=bfs(v2.y); a1[2]=bfs(v2.z); a1[3]=bfs(v2.w);
        a1[4]=bfs(v3.x); a1[5]=bfs(v3.y); a1[6]=bfs(v3.z); a1[7]=bfs(v3.w);
        short8 bf0 = gb[ks * 64 + lane];
        short8 bf1 = gb[(ks + 1) * 64 + lane];
        acc0 = __builtin_amdgcn_mfma_f32_16x16x32_bf16(a0, bf0, acc0, 0, 0, 0);
        acc1 = __builtin_amdgcn_mfma_f32_16x16x32_bf16(a1, bf1, acc1, 0, 0, 0);
    }

    if (n < NT) {
        float s2v = s2s[n];
        const float sc = 1.0f / (float)NP;
#pragma unroll
        for (int r = 0; r < 4; ++r) {
            int c = cw + kg * 4 + r;
            float val = acc0[r] + acc1[r];
            out[((size_t)b * CH + c) * NT + n] = (gamma[c] * (val - s2v) + beta[c]) * sc;
        }
    }
}

extern "C" void kernel_launch(void* const* d_in, const int* in_sizes, int n_in,
                              void* d_out, int out_size, void* d_ws, size_t ws_size,
                              hipStream_t stream) {
    const float* x     = (const float*)d_in[0];
    const float* gamma = (const float*)d_in[1];
    const float* beta  = (const float*)d_in[2];
    const float* w1    = (const float*)d_in[3];
    const float* b1    = (const float*)d_in[4];
    const float* w2    = (const float*)d_in[5];
    const float* b2    = (const float*)d_in[6];
    float* out = (float*)d_out;

    char* ws = (char*)d_ws;
    float2*         stats = (float2*)(ws + 0);                // 512 KiB
    float*          lgbuf = (float*)(ws + 524288);            // 2 MiB
    unsigned short* w1f   = (unsigned short*)(ws + 2621440);  // 144 KiB
    float*          c1    = (float*)(ws + 2768896);           // 384 B
    float*          gw1   = (float*)(ws + 2769280);           // 384 B

    k_prep<<<73,         128, 0, stream>>>(w1, gamma, beta, b1, w1f, c1, gw1);
    k_mlpf<<<BATCH * 8,  256, 0, stream>>>(x, w1f, c1, gw1, w2, b2, stats, lgbuf);
    k_outg<<<BATCH * 12, 256, 0, stream>>>(x, lgbuf, stats, gamma, beta, out);
}